// Round 2
// baseline (7765.603 us; speedup 1.0000x reference)
//
#include <hip/hip_runtime.h>
#include <hip/hip_bf16.h>
#include <hip/hip_cooperative_groups.h>

namespace cg = cooperative_groups;

// ---------------------------------------------------------------------------
// LSTM (faithful-bug variant) on MI355X — persistent cooperative version.
// carry (a, b):  a = cell chain, b = hidden chain (fed into the matmul)
//   z[g] = b_prev @ Wc[g]^T + T[x_t][g]     (T = embed-part + bias, per token)
//   g=tanh(z0) i=sig(z1) f=sig(z2) o=sig(z3)
//   a_new = g*i + a_prev*f ;  b_new = tanh(a_new)*o
// output = softmax(a_final @ w_p^T + b_p)
//
// Swapped GEMM: Zt[wcol][batch] = Wt[wcol][k] · b_prev[batch][k]
// with gate-interleaved wcol = j*4 + gate, so each lane's 4 acc regs are the
// 4 gates of one (batch, j) pair -> fully in-register state update.
// ---------------------------------------------------------------------------

typedef __attribute__((ext_vector_type(8))) short bf16x8;
typedef __attribute__((ext_vector_type(4))) float f32x4;

#define GLOBAL_AS __attribute__((address_space(1)))
#define LDS_AS    __attribute__((address_space(3)))

static __device__ __forceinline__ void async_copy16(const void* g, void* l) {
    __builtin_amdgcn_global_load_lds((const GLOBAL_AS void*)g, (LDS_AS void*)l, 16, 0, 0);
}
static __device__ __forceinline__ float sigm(float x) {
    return 1.f / (1.f + __expf(-x));
}
static __device__ __forceinline__ float tanh_fast(float x) {
    return 1.f - 2.f / (__expf(2.f * x) + 1.f);
}

// ---------------- prep 1: gate table T[s][j*4+g] (embed part + bias) -------
__global__ __launch_bounds__(256) void prep_table(
    const float* __restrict__ embed,                       // [128][256]
    const float* __restrict__ wg, const float* __restrict__ wi,
    const float* __restrict__ wf, const float* __restrict__ wo,
    const float* __restrict__ bg, const float* __restrict__ bi,
    const float* __restrict__ bff, const float* __restrict__ bo,
    float* __restrict__ T)                                 // [128][4096] interleaved
{
    __shared__ float e[256];
    const int col = blockIdx.x * 256 + threadIdx.x;        // 0..4095
    const int j = col >> 2, g = col & 3;
    const float* w = (g == 0 ? wg : g == 1 ? wi : g == 2 ? wf : wo) + (size_t)j * 1280;
    const float bias = (g == 0 ? bg : g == 1 ? bi : g == 2 ? bff : bo)[j];
    const float4* w4 = (const float4*)w;
    for (int s = 0; s < 128; ++s) {
        __syncthreads();
        e[threadIdx.x] = embed[s * 256 + threadIdx.x];
        __syncthreads();
        const float4* e4 = (const float4*)e;
        float acc = bias;
        #pragma unroll 8
        for (int d = 0; d < 64; ++d) {
            float4 ev = e4[d], wv = w4[d];
            acc += ev.x * wv.x + ev.y * wv.y + ev.z * wv.z + ev.w * wv.w;
        }
        T[(size_t)s * 4096 + col] = acc;
    }
}

// ---------------- prep 2: pack recurrent weights bf16, gate-interleaved ----
__global__ __launch_bounds__(256) void pack_w(
    const float* __restrict__ wg, const float* __restrict__ wi,
    const float* __restrict__ wf, const float* __restrict__ wo,
    __hip_bfloat16* __restrict__ Wt)                       // [4096][1024]
{
    const int col = blockIdx.x;                            // wcol = j*4+g
    const int j = col >> 2, g = col & 3;
    const float* w = (g == 0 ? wg : g == 1 ? wi : g == 2 ? wf : wo)
                     + (size_t)j * 1280 + 256;             // skip embed part
    __hip_bfloat16* out = Wt + (size_t)col * 1024;
    for (int k = threadIdx.x; k < 1024; k += 256)
        out[k] = __float2bfloat16(w[k]);
}

// ---------------- persistent fused LSTM ------------------------------------
// grid 256 (32 wcol-blocks x 8 batch-blocks), 512 threads (8 waves, 2M x 4N)
// per block: 128 wcols x 128 batch; per wave: 64 wcols x 32 batch
__global__ __launch_bounds__(512, 1) void lstm_fused(
    const __hip_bfloat16* __restrict__ Wt,   // [4096][1024]
    const float* __restrict__ T,             // [128][4096] interleaved
    const int* __restrict__ X,               // [1024][128]
    __hip_bfloat16* __restrict__ BhA,        // [1024][1024] h buffer 0 (zeroed)
    __hip_bfloat16* __restrict__ BhB,        // [1024][1024] h buffer 1
    float* __restrict__ Afin)                // [1024][1024] final cell state
{
    __shared__ __hip_bfloat16 Ws[128 * 32];
    __shared__ __hip_bfloat16 Hs[128 * 32];
    const int tid = threadIdx.x;
    const int w = tid >> 6, l = tid & 63;
    const int wm = w >> 2, wn = w & 3;               // 2 x 4 wave grid
    const int wcb = blockIdx.x & 31, bb = blockIdx.x >> 5;
    const int wcol0 = wcb * 128, batch0 = bb * 128;
    const int srow = tid >> 2;                       // staging row 0..127
    const int skoff = (tid & 3) * 8;                 // staging k elem offset

    int batchN[2], jM[4];
    #pragma unroll
    for (int n = 0; n < 2; ++n) batchN[n] = batch0 + wn * 32 + n * 16 + (l & 15);
    #pragma unroll
    for (int m = 0; m < 4; ++m) jM[m] = (wcol0 >> 2) + wm * 16 + m * 4 + (l >> 4);

    float aSt[4][2];
    #pragma unroll
    for (int m = 0; m < 4; ++m)
        #pragma unroll
        for (int n = 0; n < 2; ++n) aSt[m][n] = 0.f;

    cg::grid_group grid = cg::this_grid();
    const f32x4 z4 = {0.f, 0.f, 0.f, 0.f};

    for (int t = 0; t < 128; ++t) {
        const __hip_bfloat16* Bprev = (t & 1) ? BhB : BhA;
        __hip_bfloat16*       Bnext = (t & 1) ? BhA : BhB;

        f32x4 acc[4][2];
        #pragma unroll
        for (int m = 0; m < 4; ++m)
            #pragma unroll
            for (int n = 0; n < 2; ++n) acc[m][n] = z4;

        for (int k0 = 0; k0 < 1024; k0 += 32) {
            // stage Wt tile [128 x 32] and h tile [128 x 32] (8 KB each)
            async_copy16(Wt + (size_t)(wcol0 + srow) * 1024 + k0 + skoff, &Ws[tid * 8]);
            async_copy16(Bprev + (size_t)(batch0 + srow) * 1024 + k0 + skoff, &Hs[tid * 8]);
            __syncthreads();

            bf16x8 af[4], bf[2];
            #pragma unroll
            for (int m = 0; m < 4; ++m)
                af[m] = *(const bf16x8*)&Ws[(wm * 64 + m * 16 + (l & 15)) * 32 + (l >> 4) * 8];
            #pragma unroll
            for (int n = 0; n < 2; ++n)
                bf[n] = *(const bf16x8*)&Hs[(wn * 32 + n * 16 + (l & 15)) * 32 + (l >> 4) * 8];
            #pragma unroll
            for (int m = 0; m < 4; ++m)
                #pragma unroll
                for (int n = 0; n < 2; ++n)
                    acc[m][n] = __builtin_amdgcn_mfma_f32_16x16x32_bf16(
                        af[m], bf[n], acc[m][n], 0, 0, 0);
            __syncthreads();
        }

        // in-register epilogue: lane holds gates g=0..3 in acc regs 0..3
        // for (batch = batchN[n], j = jM[m])
        #pragma unroll
        for (int n = 0; n < 2; ++n) {
            const int s = X[batchN[n] * 128 + t];
            const float* Ts = T + (size_t)s * 4096;
            #pragma unroll
            for (int m = 0; m < 4; ++m) {
                const float4 tv = *(const float4*)&Ts[jM[m] * 4];
                const float z0 = acc[m][n][0] + tv.x;
                const float z1 = acc[m][n][1] + tv.y;
                const float z2 = acc[m][n][2] + tv.z;
                const float z3 = acc[m][n][3] + tv.w;
                const float gg = tanh_fast(z0);
                const float ii = sigm(z1);
                const float ff = sigm(z2);
                const float oo = sigm(z3);
                const float na = gg * ii + aSt[m][n] * ff;
                aSt[m][n] = na;
                Bnext[(size_t)batchN[n] * 1024 + jM[m]] =
                    __float2bfloat16(tanh_fast(na) * oo);
            }
        }
        grid.sync();
    }

    #pragma unroll
    for (int n = 0; n < 2; ++n)
        #pragma unroll
        for (int m = 0; m < 4; ++m)
            Afin[(size_t)batchN[n] * 1024 + jM[m]] = aSt[m][n];
}

// ---------------- final projection + softmax -------------------------------
__global__ __launch_bounds__(256) void proj_softmax(
    const float* __restrict__ A,             // [1024][1024]
    const float* __restrict__ Wp,            // [10][1024]
    const float* __restrict__ bp,            // [10]
    float* __restrict__ out)                 // [1024][10]
{
    const int row = blockIdx.x;
    const float* a = A + (size_t)row * 1024;
    float p[10];
    #pragma unroll
    for (int c = 0; c < 10; ++c) p[c] = 0.f;
    for (int k = threadIdx.x; k < 1024; k += 256) {
        const float av = a[k];
        #pragma unroll
        for (int c = 0; c < 10; ++c) p[c] += av * Wp[c * 1024 + k];
    }
    #pragma unroll
    for (int c = 0; c < 10; ++c)
        #pragma unroll
        for (int off = 32; off; off >>= 1) p[c] += __shfl_down(p[c], off);
    __shared__ float red[4][10];
    const int wv = threadIdx.x >> 6, ln = threadIdx.x & 63;
    if (ln == 0)
        for (int c = 0; c < 10; ++c) red[wv][c] = p[c];
    __syncthreads();
    if (threadIdx.x == 0) {
        float logits[10], mx = -1e30f;
        for (int c = 0; c < 10; ++c) {
            logits[c] = red[0][c] + red[1][c] + red[2][c] + red[3][c] + bp[c];
            mx = fmaxf(mx, logits[c]);
        }
        float sum = 0.f;
        for (int c = 0; c < 10; ++c) { logits[c] = __expf(logits[c] - mx); sum += logits[c]; }
        const float inv = 1.f / sum;
        for (int c = 0; c < 10; ++c) out[(size_t)row * 10 + c] = logits[c] * inv;
    }
}

// ---------------------------------------------------------------------------
extern "C" void kernel_launch(void* const* d_in, const int* in_sizes, int n_in,
                              void* d_out, int out_size, void* d_ws, size_t ws_size,
                              hipStream_t stream) {
    (void)in_sizes; (void)n_in; (void)out_size; (void)ws_size;
    const int*   x     = (const int*)d_in[0];
    const float* embed = (const float*)d_in[1];
    const float* wg    = (const float*)d_in[2];
    const float* wi    = (const float*)d_in[3];
    const float* wf    = (const float*)d_in[4];
    const float* wo    = (const float*)d_in[5];
    const float* bg    = (const float*)d_in[6];
    const float* bi    = (const float*)d_in[7];
    const float* bff   = (const float*)d_in[8];
    const float* bo    = (const float*)d_in[9];
    const float* wp    = (const float*)d_in[10];
    const float* bp    = (const float*)d_in[11];
    float* out = (float*)d_out;

    char* ws = (char*)d_ws;
    float*          T    = (float*)(ws);                        // 2 MB  [128][4096]
    __hip_bfloat16* Wt   = (__hip_bfloat16*)(ws + (2u << 20));  // 8 MB  [4096][1024]
    __hip_bfloat16* BhA  = (__hip_bfloat16*)(ws + (10u << 20)); // 2 MB
    __hip_bfloat16* BhB  = (__hip_bfloat16*)(ws + (12u << 20)); // 2 MB
    float*          Afin = (float*)(ws + (14u << 20));          // 4 MB

    prep_table<<<16, 256, 0, stream>>>(embed, wg, wi, wf, wo, bg, bi, bff, bo, T);
    pack_w<<<4096, 256, 0, stream>>>(wg, wi, wf, wo, Wt);
    hipMemsetAsync(BhA, 0, (size_t)1024 * 1024 * sizeof(__hip_bfloat16), stream);

    void* args[] = {(void*)&Wt, (void*)&T, (void*)&x, (void*)&BhA, (void*)&BhB, (void*)&Afin};
    hipLaunchCooperativeKernel((void*)lstm_fused, dim3(256), dim3(512), args, 0, stream);

    proj_softmax<<<1024, 256, 0, stream>>>(Afin, wp, bp, out);
}

// Round 3
// 3246.325 us; speedup vs baseline: 2.3921x; 2.3921x over previous
//
#include <hip/hip_runtime.h>
#include <hip/hip_bf16.h>

// ---------------------------------------------------------------------------
// LSTM (faithful-bug variant) on MI355X — fused per-step kernel.
// carry (a, b):  a = cell chain, b = hidden chain (fed into the matmul)
//   z[g] = b_prev @ Wc[g]^T + T[x_t][g]     (T = embed-part + bias, per token)
//   g=tanh(z0) i=sig(z1) f=sig(z2) o=sig(z3)
//   a_new = g*i + a_prev*f ;  b_new = tanh(a_new)*o
// output = softmax(a_final @ w_p^T + b_p)
//
// Swapped GEMM Zt[wcol][batch] = Wt[wcol][k] · h_prev[batch][k], wcol = j*4+g
// so each lane's 4 acc regs are the 4 gates of one (batch, j) pair.
// Per step: ONE kernel, grid 256 (1 block/CU), tile 128 wcol x 128 batch,
// BK=64, double-buffered LDS with XOR-swizzled layout, prefetch pipeline.
// Cell state lives in a per-thread-coalesced blob between launches.
// ---------------------------------------------------------------------------

typedef __attribute__((ext_vector_type(8))) short bf16x8;
typedef __attribute__((ext_vector_type(4))) float f32x4;

#define GLOBAL_AS __attribute__((address_space(1)))
#define LDS_AS    __attribute__((address_space(3)))

static __device__ __forceinline__ void async_copy16(const void* g, void* l) {
    __builtin_amdgcn_global_load_lds((const GLOBAL_AS void*)g, (LDS_AS void*)l, 16, 0, 0);
}
static __device__ __forceinline__ float sigm(float x) {
    return 1.f / (1.f + __expf(-x));
}
static __device__ __forceinline__ float tanh_fast(float x) {
    return 1.f - 2.f / (__expf(2.f * x) + 1.f);
}

// ---------------- prep 1: gate table T[s][j*4+g] (embed part + bias) -------
__global__ __launch_bounds__(256) void prep_table(
    const float* __restrict__ embed,                       // [128][256]
    const float* __restrict__ wg, const float* __restrict__ wi,
    const float* __restrict__ wf, const float* __restrict__ wo,
    const float* __restrict__ bg, const float* __restrict__ bi,
    const float* __restrict__ bff, const float* __restrict__ bo,
    float* __restrict__ T)                                 // [128][4096] interleaved
{
    __shared__ float e[256];
    const int col = blockIdx.x * 256 + threadIdx.x;        // 0..4095
    const int j = col >> 2, g = col & 3;
    const float* w = (g == 0 ? wg : g == 1 ? wi : g == 2 ? wf : wo) + (size_t)j * 1280;
    const float bias = (g == 0 ? bg : g == 1 ? bi : g == 2 ? bff : bo)[j];
    const float4* w4 = (const float4*)w;
    for (int s = 0; s < 128; ++s) {
        __syncthreads();
        e[threadIdx.x] = embed[s * 256 + threadIdx.x];
        __syncthreads();
        const float4* e4 = (const float4*)e;
        float acc = bias;
        #pragma unroll 8
        for (int d = 0; d < 64; ++d) {
            float4 ev = e4[d], wv = w4[d];
            acc += ev.x * wv.x + ev.y * wv.y + ev.z * wv.z + ev.w * wv.w;
        }
        T[(size_t)s * 4096 + col] = acc;
    }
}

// ---------------- prep 2: pack recurrent weights bf16, gate-interleaved ----
__global__ __launch_bounds__(256) void pack_w(
    const float* __restrict__ wg, const float* __restrict__ wi,
    const float* __restrict__ wf, const float* __restrict__ wo,
    __hip_bfloat16* __restrict__ Wt)                       // [4096][1024]
{
    const int col = blockIdx.x;                            // wcol = j*4+g
    const int j = col >> 2, g = col & 3;
    const float* w = (g == 0 ? wg : g == 1 ? wi : g == 2 ? wf : wo)
                     + (size_t)j * 1280 + 256;             // skip embed part
    __hip_bfloat16* out = Wt + (size_t)col * 1024;
    for (int k = threadIdx.x; k < 1024; k += 256)
        out[k] = __float2bfloat16(w[k]);
}

// ---------------- fused LSTM step ------------------------------------------
// grid 256: wcb = bid&31 (128 wcols), bb = bid>>5 (128 batch). 512 threads,
// 8 waves in 2(wm) x 4(wn); wave tile 64 wcol x 32 batch.
// LDS per buffer: Ws 128x64 bf16 (16KB, swizzled) + Hs 128x64 (16KB).
__global__ __launch_bounds__(512, 2) void step_fused(
    const __hip_bfloat16* __restrict__ Wt,   // [4096][1024]
    const float* __restrict__ T,             // [128][4096] interleaved
    const int* __restrict__ X,               // [1024][128]
    const __hip_bfloat16* __restrict__ Hprev,// [1024][1024]
    __hip_bfloat16* __restrict__ Hnext,      // [1024][1024]
    float* __restrict__ CSblob,              // [256*512*8] per-thread cell state
    float* __restrict__ CSout,               // [1024][1024], written at t==127
    int t)
{
    __shared__ char lds[2][32768];           // [buf]{ Ws 16KB | Hs 16KB }
    const int tid = threadIdx.x;
    const int w = tid >> 6, l = tid & 63;
    const int wm = w >> 2, wn = w & 3;
    const int wcol0 = (blockIdx.x & 31) * 128;
    const int batch0 = (blockIdx.x >> 5) * 128;

    // ---- issue k-tile 0 staging ASAP -------------------------------------
    // slot s: row = s>>3, chunk = s&7 (16B chunks of the 128B row).
    // Swizzle: LDS is linear in s; the global SOURCE k-chunk is chunk^(row&7),
    // the reader applies the same XOR -> involution cancels (rule 21).
    {
        #pragma unroll
        for (int i = 0; i < 2; ++i) {
            const int s = tid + i * 512;
            const int row = s >> 3, ch = s & 7;
            const int kq = (ch ^ (row & 7)) << 3;     // k elem offset 0..56
            async_copy16(Wt + (size_t)(wcol0 + row) * 1024 + kq, &lds[0][s * 16]);
            async_copy16(Hprev + (size_t)(batch0 + row) * 1024 + kq,
                         &lds[0][16384 + s * 16]);
        }
    }

    // ---- epilogue inputs: load now, consumed ~12K cycles later ------------
    int batchN[2], jM[4];
    #pragma unroll
    for (int n = 0; n < 2; ++n) batchN[n] = batch0 + wn * 32 + n * 16 + (l & 15);
    #pragma unroll
    for (int m = 0; m < 4; ++m) jM[m] = (wcol0 >> 2) + wm * 16 + m * 4 + (l >> 4);

    f32x4 tv[4][2];
    float ap[4][2];
    #pragma unroll
    for (int n = 0; n < 2; ++n) {
        const int s = X[batchN[n] * 128 + t];
        #pragma unroll
        for (int m = 0; m < 4; ++m)
            tv[m][n] = *(const f32x4*)&T[(size_t)s * 4096 + jM[m] * 4];
    }
    float* blob = CSblob + ((size_t)blockIdx.x * 512 + tid) * 8;
    if (t > 0) {
        #pragma unroll
        for (int m = 0; m < 4; ++m)
            #pragma unroll
            for (int n = 0; n < 2; ++n) ap[m][n] = blob[m * 2 + n];
    } else {
        #pragma unroll
        for (int m = 0; m < 4; ++m)
            #pragma unroll
            for (int n = 0; n < 2; ++n) ap[m][n] = 0.f;
    }

    f32x4 acc[4][2];
    const f32x4 z4 = {0.f, 0.f, 0.f, 0.f};
    #pragma unroll
    for (int m = 0; m < 4; ++m)
        #pragma unroll
        for (int n = 0; n < 2; ++n) acc[m][n] = z4;

    __syncthreads();                          // implicit vmcnt(0): tile 0 ready

    // ---- K loop: 16 tiles of BK=64, stage-ahead, 1 barrier per tile -------
    int cur = 0;
    for (int kt = 0; kt < 16; ++kt) {
        if (kt < 15) {
            const int k0 = (kt + 1) * 64;
            #pragma unroll
            for (int i = 0; i < 2; ++i) {
                const int s = tid + i * 512;
                const int row = s >> 3, ch = s & 7;
                const int kq = k0 + ((ch ^ (row & 7)) << 3);
                async_copy16(Wt + (size_t)(wcol0 + row) * 1024 + kq,
                             &lds[cur ^ 1][s * 16]);
                async_copy16(Hprev + (size_t)(batch0 + row) * 1024 + kq,
                             &lds[cur ^ 1][16384 + s * 16]);
            }
        }
        const char* base = &lds[cur][0];
        #pragma unroll
        for (int kk = 0; kk < 2; ++kk) {
            bf16x8 af[4], bfr[2];
            #pragma unroll
            for (int m = 0; m < 4; ++m) {
                const int row = wm * 64 + m * 16 + (l & 15);
                const int ch = (kk * 4 + (l >> 4)) ^ (row & 7);
                af[m] = *(const bf16x8*)(base + (row * 8 + ch) * 16);
            }
            #pragma unroll
            for (int n = 0; n < 2; ++n) {
                const int row = wn * 32 + n * 16 + (l & 15);
                const int ch = (kk * 4 + (l >> 4)) ^ (row & 7);
                bfr[n] = *(const bf16x8*)(base + 16384 + (row * 8 + ch) * 16);
            }
            #pragma unroll
            for (int m = 0; m < 4; ++m)
                #pragma unroll
                for (int n = 0; n < 2; ++n)
                    acc[m][n] = __builtin_amdgcn_mfma_f32_16x16x32_bf16(
                        af[m], bfr[n], acc[m][n], 0, 0, 0);
        }
        if (kt < 15) __syncthreads();         // drains next-tile staging too
        cur ^= 1;
    }

    // ---- in-register epilogue --------------------------------------------
    #pragma unroll
    for (int m = 0; m < 4; ++m)
        #pragma unroll
        for (int n = 0; n < 2; ++n) {
            const float z0 = acc[m][n][0] + tv[m][n][0];
            const float z1 = acc[m][n][1] + tv[m][n][1];
            const float z2 = acc[m][n][2] + tv[m][n][2];
            const float z3 = acc[m][n][3] + tv[m][n][3];
            const float gg = tanh_fast(z0);
            const float ii = sigm(z1);
            const float ff = sigm(z2);
            const float oo = sigm(z3);
            const float na = gg * ii + ap[m][n] * ff;
            blob[m * 2 + n] = na;
            Hnext[(size_t)batchN[n] * 1024 + jM[m]] =
                __float2bfloat16(tanh_fast(na) * oo);
            if (t == 127)
                CSout[(size_t)batchN[n] * 1024 + jM[m]] = na;
        }
}

// ---------------- final projection + softmax -------------------------------
__global__ __launch_bounds__(256) void proj_softmax(
    const float* __restrict__ A,             // [1024][1024]
    const float* __restrict__ Wp,            // [10][1024]
    const float* __restrict__ bp,            // [10]
    float* __restrict__ out)                 // [1024][10]
{
    const int row = blockIdx.x;
    const float* a = A + (size_t)row * 1024;
    float p[10];
    #pragma unroll
    for (int c = 0; c < 10; ++c) p[c] = 0.f;
    for (int k = threadIdx.x; k < 1024; k += 256) {
        const float av = a[k];
        #pragma unroll
        for (int c = 0; c < 10; ++c) p[c] += av * Wp[c * 1024 + k];
    }
    #pragma unroll
    for (int c = 0; c < 10; ++c)
        #pragma unroll
        for (int off = 32; off; off >>= 1) p[c] += __shfl_down(p[c], off);
    __shared__ float red[4][10];
    const int wv = threadIdx.x >> 6, ln = threadIdx.x & 63;
    if (ln == 0)
        for (int c = 0; c < 10; ++c) red[wv][c] = p[c];
    __syncthreads();
    if (threadIdx.x == 0) {
        float logits[10], mx = -1e30f;
        for (int c = 0; c < 10; ++c) {
            logits[c] = red[0][c] + red[1][c] + red[2][c] + red[3][c] + bp[c];
            mx = fmaxf(mx, logits[c]);
        }
        float sum = 0.f;
        for (int c = 0; c < 10; ++c) { logits[c] = __expf(logits[c] - mx); sum += logits[c]; }
        const float inv = 1.f / sum;
        for (int c = 0; c < 10; ++c) out[(size_t)row * 10 + c] = logits[c] * inv;
    }
}

// ---------------------------------------------------------------------------
extern "C" void kernel_launch(void* const* d_in, const int* in_sizes, int n_in,
                              void* d_out, int out_size, void* d_ws, size_t ws_size,
                              hipStream_t stream) {
    (void)in_sizes; (void)n_in; (void)out_size; (void)ws_size;
    const int*   x     = (const int*)d_in[0];
    const float* embed = (const float*)d_in[1];
    const float* wg    = (const float*)d_in[2];
    const float* wi    = (const float*)d_in[3];
    const float* wf    = (const float*)d_in[4];
    const float* wo    = (const float*)d_in[5];
    const float* bg    = (const float*)d_in[6];
    const float* bi    = (const float*)d_in[7];
    const float* bff   = (const float*)d_in[8];
    const float* bo    = (const float*)d_in[9];
    const float* wp    = (const float*)d_in[10];
    const float* bp    = (const float*)d_in[11];
    float* out = (float*)d_out;

    char* ws = (char*)d_ws;
    float*          T    = (float*)(ws);                        // 2 MB
    __hip_bfloat16* Wt   = (__hip_bfloat16*)(ws + (2u << 20));  // 8 MB
    __hip_bfloat16* BhA  = (__hip_bfloat16*)(ws + (10u << 20)); // 2 MB
    __hip_bfloat16* BhB  = (__hip_bfloat16*)(ws + (12u << 20)); // 2 MB
    float*          CSo  = (float*)(ws + (14u << 20));          // 4 MB
    float*          CSb  = (float*)(ws + (18u << 20));          // 4 MB

    prep_table<<<16, 256, 0, stream>>>(embed, wg, wi, wf, wo, bg, bi, bff, bo, T);
    pack_w<<<4096, 256, 0, stream>>>(wg, wi, wf, wo, Wt);
    hipMemsetAsync(BhA, 0, (size_t)1024 * 1024 * sizeof(__hip_bfloat16), stream);

    for (int t = 0; t < 128; ++t) {
        const __hip_bfloat16* Hp = (t & 1) ? BhB : BhA;
        __hip_bfloat16*       Hn = (t & 1) ? BhA : BhB;
        step_fused<<<256, 512, 0, stream>>>(Wt, T, x, Hp, Hn, CSb, CSo, t);
    }
    proj_softmax<<<1024, 256, 0, stream>>>(CSo, wp, bp, out);
}

// Round 4
// 2248.768 us; speedup vs baseline: 3.4533x; 1.4436x over previous
//
#include <hip/hip_runtime.h>
#include <hip/hip_bf16.h>

// ---------------------------------------------------------------------------
// LSTM (faithful-bug variant) on MI355X — fused per-step kernel, v2.
// carry (a, b):  a = cell chain, b = hidden chain (fed into the matmul)
//   z[g] = b_prev @ Wc[g]^T + T[x_t][g]     (T = embed-part + bias, per token)
//   g=tanh(z0) i=sig(z1) f=sig(z2) o=sig(z3)
//   a_new = g*i + a_prev*f ;  b_new = tanh(a_new)*o
// output = softmax(a_final @ w_p^T + b_p)
//
// Swapped GEMM Zt[wcol][batch] = Wt[wcol][k] · h_prev[batch][k], wcol = j*4+g
// so each lane's 4 acc regs are the 4 gates of one (batch, j) pair.
// v2: grid 512 (2 blocks/CU), tile 128 wcol x 64 batch, BK=64 double-buffer,
// counted-vmcnt schedule (no full drain in the K loop), XOR-swizzled LDS.
// ---------------------------------------------------------------------------

typedef __attribute__((ext_vector_type(8))) short bf16x8;
typedef __attribute__((ext_vector_type(4))) float f32x4;

#define GLOBAL_AS __attribute__((address_space(1)))
#define LDS_AS    __attribute__((address_space(3)))

static __device__ __forceinline__ void async_copy16(const void* g, void* l) {
    __builtin_amdgcn_global_load_lds((const GLOBAL_AS void*)g, (LDS_AS void*)l, 16, 0, 0);
}
static __device__ __forceinline__ float sigm(float x) {
    return 1.f / (1.f + __expf(-x));
}
static __device__ __forceinline__ float tanh_fast(float x) {
    return 1.f - 2.f / (__expf(2.f * x) + 1.f);
}

// ---------------- prep 1: gate table T[s][j*4+g] (embed part + bias) -------
// grid (16 colblocks, 16 s-blocks) x 256 threads; 8 s-rows per block.
__global__ __launch_bounds__(256) void prep_table(
    const float* __restrict__ embed,                       // [128][256]
    const float* __restrict__ wg, const float* __restrict__ wi,
    const float* __restrict__ wf, const float* __restrict__ wo,
    const float* __restrict__ bg, const float* __restrict__ bi,
    const float* __restrict__ bff, const float* __restrict__ bo,
    float* __restrict__ T)                                 // [128][4096] interleaved
{
    __shared__ float e[8][256];
    const int tid = threadIdx.x;
    const int col = blockIdx.x * 256 + tid;                // 0..4095
    const int s0 = blockIdx.y * 8;
    const int j = col >> 2, g = col & 3;
    const float* w = (g == 0 ? wg : g == 1 ? wi : g == 2 ? wf : wo) + (size_t)j * 1280;
    const float bias = (g == 0 ? bg : g == 1 ? bi : g == 2 ? bff : bo)[j];
    #pragma unroll
    for (int i = 0; i < 8; ++i) e[i][tid] = embed[(s0 + i) * 256 + tid];
    __syncthreads();
    const float4* w4 = (const float4*)w;
    float acc[8];
    #pragma unroll
    for (int i = 0; i < 8; ++i) acc[i] = bias;
    for (int d = 0; d < 64; ++d) {
        const float4 wv = w4[d];
        #pragma unroll
        for (int i = 0; i < 8; ++i) {
            const float4 ev = ((const float4*)e[i])[d];
            acc[i] += ev.x * wv.x + ev.y * wv.y + ev.z * wv.z + ev.w * wv.w;
        }
    }
    #pragma unroll
    for (int i = 0; i < 8; ++i)
        T[(size_t)(s0 + i) * 4096 + col] = acc[i];
}

// ---------------- prep 2: pack recurrent weights bf16, gate-interleaved ----
__global__ __launch_bounds__(256) void pack_w(
    const float* __restrict__ wg, const float* __restrict__ wi,
    const float* __restrict__ wf, const float* __restrict__ wo,
    __hip_bfloat16* __restrict__ Wt)                       // [4096][1024]
{
    const int col = blockIdx.x;                            // wcol = j*4+g
    const int j = col >> 2, g = col & 3;
    const float* w = (g == 0 ? wg : g == 1 ? wi : g == 2 ? wf : wo)
                     + (size_t)j * 1280 + 256;             // skip embed part
    __hip_bfloat16* out = Wt + (size_t)col * 1024;
    for (int k = threadIdx.x; k < 1024; k += 256)
        out[k] = __float2bfloat16(w[k]);
}

// ---------------- fused LSTM step ------------------------------------------
// grid 512: wcb = bid&31 (128 wcols), bb = bid>>5 (64 batch). 512 threads,
// 8 waves in 4(wm) x 2(wn); wave tile 32 wcol x 32 batch, acc[2][2].
// LDS per buffer: Ws 128x64 bf16 (16KB, swizzled) + Hs 64x64 (8KB) = 24KB.
__global__ __launch_bounds__(512, 4) void step_fused(
    const __hip_bfloat16* __restrict__ Wt,   // [4096][1024]
    const float* __restrict__ T,             // [128][4096] interleaved
    const int* __restrict__ X,               // [1024][128]
    const __hip_bfloat16* __restrict__ Hprev,// [1024][1024]
    __hip_bfloat16* __restrict__ Hnext,      // [1024][1024]
    float* __restrict__ CSblob,              // [512*512*4] per-thread cell state
    float* __restrict__ CSout,               // [1024][1024], written at t==127
    int t)
{
    __shared__ char lds[2][24576];           // [buf]{ Ws 16KB | Hs 8KB }
    const int tid = threadIdx.x;
    const int w = tid >> 6, l = tid & 63;
    const int wm = w >> 1, wn = w & 1;
    const int wcol0 = (blockIdx.x & 31) * 128;
    const int batch0 = (blockIdx.x >> 5) * 64;

    // slot s: row = s>>3, chunk = s&7 (16B chunks of the 128B row).
    // LDS dest linear in s; global SOURCE chunk is ch^(row&7); reader applies
    // the same XOR -> involution cancels (rule 21).
#define STAGE(K0, BUF) do {                                                    \
        _Pragma("unroll")                                                      \
        for (int i_ = 0; i_ < 2; ++i_) {                                       \
            const int sW = tid + i_ * 512;                                     \
            const int rW = sW >> 3, cW = sW & 7;                               \
            async_copy16(Wt + (size_t)(wcol0 + rW) * 1024 + (K0)               \
                             + ((cW ^ (rW & 7)) << 3),                         \
                         &lds[BUF][sW * 16]);                                  \
        }                                                                      \
        const int sH = tid;                                                    \
        const int rH = sH >> 3, cH = sH & 7;                                   \
        async_copy16(Hprev + (size_t)(batch0 + rH) * 1024 + (K0)               \
                         + ((cH ^ (rH & 7)) << 3),                             \
                     &lds[BUF][16384 + sH * 16]);                              \
    } while (0)

    // ---- epilogue inputs first (retired before staging so vmcnt stays exact)
    int batchN[2], jM[2];
    #pragma unroll
    for (int n = 0; n < 2; ++n) batchN[n] = batch0 + wn * 32 + n * 16 + (l & 15);
    #pragma unroll
    for (int m = 0; m < 2; ++m) jM[m] = (wcol0 >> 2) + wm * 8 + m * 4 + (l >> 4);

    f32x4 tv[2][2];
    float ap[2][2];
    #pragma unroll
    for (int n = 0; n < 2; ++n) {
        const int s = X[batchN[n] * 128 + t];
        #pragma unroll
        for (int m = 0; m < 2; ++m)
            tv[m][n] = *(const f32x4*)&T[(size_t)s * 4096 + jM[m] * 4];
    }
    float* blob = CSblob + ((size_t)blockIdx.x * 512 + tid) * 4;
    if (t > 0) {
        #pragma unroll
        for (int m = 0; m < 2; ++m)
            #pragma unroll
            for (int n = 0; n < 2; ++n) ap[m][n] = blob[m * 2 + n];
    } else {
        #pragma unroll
        for (int m = 0; m < 2; ++m)
            #pragma unroll
            for (int n = 0; n < 2; ++n) ap[m][n] = 0.f;
    }
    asm volatile("s_waitcnt vmcnt(0)" ::: "memory");

    // ---- prologue: tile 0 -------------------------------------------------
    STAGE(0, 0);
    asm volatile("s_waitcnt vmcnt(0)" ::: "memory");
    __builtin_amdgcn_s_barrier();

    f32x4 acc[2][2];
    const f32x4 z4 = {0.f, 0.f, 0.f, 0.f};
    #pragma unroll
    for (int m = 0; m < 2; ++m)
        #pragma unroll
        for (int n = 0; n < 2; ++n) acc[m][n] = z4;

    // ---- K loop: 16 tiles of BK=64, counted-vmcnt, 2 barriers/tile --------
    #pragma unroll
    for (int kt = 0; kt < 16; ++kt) {
        if (kt < 15) STAGE((kt + 1) * 64, (kt + 1) & 1);
        if (kt == 15)     asm volatile("s_waitcnt vmcnt(0)" ::: "memory");
        else if (kt > 0)  asm volatile("s_waitcnt vmcnt(3)" ::: "memory");
        if (kt > 0) __builtin_amdgcn_s_barrier();   // all waves' tile-kt loads in LDS

        const char* base = &lds[kt & 1][0];
        #pragma unroll
        for (int kk = 0; kk < 2; ++kk) {
            bf16x8 af[2], bfr[2];
            #pragma unroll
            for (int m = 0; m < 2; ++m) {
                const int row = wm * 32 + m * 16 + (l & 15);
                const int ch = (kk * 4 + (l >> 4)) ^ (row & 7);
                af[m] = *(const bf16x8*)(base + (row * 8 + ch) * 16);
            }
            #pragma unroll
            for (int n = 0; n < 2; ++n) {
                const int row = wn * 32 + n * 16 + (l & 15);
                const int ch = (kk * 4 + (l >> 4)) ^ (row & 7);
                bfr[n] = *(const bf16x8*)(base + 16384 + (row * 8 + ch) * 16);
            }
            #pragma unroll
            for (int m = 0; m < 2; ++m)
                #pragma unroll
                for (int n = 0; n < 2; ++n)
                    acc[m][n] = __builtin_amdgcn_mfma_f32_16x16x32_bf16(
                        af[m], bfr[n], acc[m][n], 0, 0, 0);
        }
        if (kt < 15) __builtin_amdgcn_s_barrier();  // reads of this buf done
    }
#undef STAGE

    // ---- in-register epilogue --------------------------------------------
    #pragma unroll
    for (int m = 0; m < 2; ++m)
        #pragma unroll
        for (int n = 0; n < 2; ++n) {
            const float z0 = acc[m][n][0] + tv[m][n][0];
            const float z1 = acc[m][n][1] + tv[m][n][1];
            const float z2 = acc[m][n][2] + tv[m][n][2];
            const float z3 = acc[m][n][3] + tv[m][n][3];
            const float gg = tanh_fast(z0);
            const float ii = sigm(z1);
            const float ff = sigm(z2);
            const float oo = sigm(z3);
            const float na = gg * ii + ap[m][n] * ff;
            blob[m * 2 + n] = na;
            Hnext[(size_t)batchN[n] * 1024 + jM[m]] =
                __float2bfloat16(tanh_fast(na) * oo);
            if (t == 127)
                CSout[(size_t)batchN[n] * 1024 + jM[m]] = na;
        }
}

// ---------------- final projection + softmax -------------------------------
__global__ __launch_bounds__(256) void proj_softmax(
    const float* __restrict__ A,             // [1024][1024]
    const float* __restrict__ Wp,            // [10][1024]
    const float* __restrict__ bp,            // [10]
    float* __restrict__ out)                 // [1024][10]
{
    const int row = blockIdx.x;
    const float* a = A + (size_t)row * 1024;
    float p[10];
    #pragma unroll
    for (int c = 0; c < 10; ++c) p[c] = 0.f;
    for (int k = threadIdx.x; k < 1024; k += 256) {
        const float av = a[k];
        #pragma unroll
        for (int c = 0; c < 10; ++c) p[c] += av * Wp[c * 1024 + k];
    }
    #pragma unroll
    for (int c = 0; c < 10; ++c)
        #pragma unroll
        for (int off = 32; off; off >>= 1) p[c] += __shfl_down(p[c], off);
    __shared__ float red[4][10];
    const int wv = threadIdx.x >> 6, ln = threadIdx.x & 63;
    if (ln == 0)
        for (int c = 0; c < 10; ++c) red[wv][c] = p[c];
    __syncthreads();
    if (threadIdx.x == 0) {
        float logits[10], mx = -1e30f;
        for (int c = 0; c < 10; ++c) {
            logits[c] = red[0][c] + red[1][c] + red[2][c] + red[3][c] + bp[c];
            mx = fmaxf(mx, logits[c]);
        }
        float sum = 0.f;
        for (int c = 0; c < 10; ++c) { logits[c] = __expf(logits[c] - mx); sum += logits[c]; }
        const float inv = 1.f / sum;
        for (int c = 0; c < 10; ++c) out[(size_t)row * 10 + c] = logits[c] * inv;
    }
}

// ---------------------------------------------------------------------------
extern "C" void kernel_launch(void* const* d_in, const int* in_sizes, int n_in,
                              void* d_out, int out_size, void* d_ws, size_t ws_size,
                              hipStream_t stream) {
    (void)in_sizes; (void)n_in; (void)out_size; (void)ws_size;
    const int*   x     = (const int*)d_in[0];
    const float* embed = (const float*)d_in[1];
    const float* wg    = (const float*)d_in[2];
    const float* wi    = (const float*)d_in[3];
    const float* wf    = (const float*)d_in[4];
    const float* wo    = (const float*)d_in[5];
    const float* bg    = (const float*)d_in[6];
    const float* bi    = (const float*)d_in[7];
    const float* bff   = (const float*)d_in[8];
    const float* bo    = (const float*)d_in[9];
    const float* wp    = (const float*)d_in[10];
    const float* bp    = (const float*)d_in[11];
    float* out = (float*)d_out;

    char* ws = (char*)d_ws;
    float*          T    = (float*)(ws);                        // 2 MB
    __hip_bfloat16* Wt   = (__hip_bfloat16*)(ws + (2u << 20));  // 8 MB
    __hip_bfloat16* BhA  = (__hip_bfloat16*)(ws + (10u << 20)); // 2 MB
    __hip_bfloat16* BhB  = (__hip_bfloat16*)(ws + (12u << 20)); // 2 MB
    float*          CSo  = (float*)(ws + (14u << 20));          // 4 MB
    float*          CSb  = (float*)(ws + (18u << 20));          // 4 MB

    prep_table<<<dim3(16, 16), 256, 0, stream>>>(embed, wg, wi, wf, wo, bg, bi, bff, bo, T);
    pack_w<<<4096, 256, 0, stream>>>(wg, wi, wf, wo, Wt);
    hipMemsetAsync(BhA, 0, (size_t)1024 * 1024 * sizeof(__hip_bfloat16), stream);

    for (int t = 0; t < 128; ++t) {
        const __hip_bfloat16* Hp = (t & 1) ? BhB : BhA;
        __hip_bfloat16*       Hn = (t & 1) ? BhA : BhB;
        step_fused<<<512, 512, 0, stream>>>(Wt, T, x, Hp, Hn, CSb, CSo, t);
    }
    proj_softmax<<<1024, 256, 0, stream>>>(CSo, wp, bp, out);
}

// Round 5
// 2224.803 us; speedup vs baseline: 3.4905x; 1.0108x over previous
//
#include <hip/hip_runtime.h>
#include <hip/hip_bf16.h>

// ---------------------------------------------------------------------------
// LSTM (faithful-bug variant) on MI355X — fused per-step kernel, v3.
// carry (a, b):  a = cell chain, b = hidden chain (fed into the matmul)
//   z[g] = b_prev @ Wc[g]^T + T[x_t][g]     (T = embed-part + bias, per token)
//   g=tanh(z0) i=sig(z1) f=sig(z2) o=sig(z3)
//   a_new = g*i + a_prev*f ;  b_new = tanh(a_new)*o
// output = softmax(a_final @ w_p^T + b_p)
//
// Swapped GEMM Zt[wcol][batch] = Wt[wcol][k] · h_prev[batch][k], wcol = j*4+g
// so each lane's 4 acc regs are the 4 gates of one (batch, j) pair.
// v3: XCD-aware block decode — XCD k (bid&7) owns wcol-blocks [4k,4k+4) x all
// batch-blocks, so its W slice (1MB) + H (2MB) fit the 4MB per-XCD L2.
// Tile 128 wcol x 64 batch, BK=64 double-buffer, counted-vmcnt, XOR swizzle.
// ---------------------------------------------------------------------------

typedef __attribute__((ext_vector_type(8))) short bf16x8;
typedef __attribute__((ext_vector_type(4))) float f32x4;

#define GLOBAL_AS __attribute__((address_space(1)))
#define LDS_AS    __attribute__((address_space(3)))

static __device__ __forceinline__ void async_copy16(const void* g, void* l) {
    __builtin_amdgcn_global_load_lds((const GLOBAL_AS void*)g, (LDS_AS void*)l, 16, 0, 0);
}
static __device__ __forceinline__ float sigm(float x) {
    return 1.f / (1.f + __expf(-x));
}
static __device__ __forceinline__ float tanh_fast(float x) {
    return 1.f - 2.f / (__expf(2.f * x) + 1.f);
}

// ---------------- prep 1: gate table T[s][j*4+g] (embed part + bias) -------
// grid (16 colblocks, 16 s-blocks) x 256 threads; 8 s-rows per block.
__global__ __launch_bounds__(256) void prep_table(
    const float* __restrict__ embed,                       // [128][256]
    const float* __restrict__ wg, const float* __restrict__ wi,
    const float* __restrict__ wf, const float* __restrict__ wo,
    const float* __restrict__ bg, const float* __restrict__ bi,
    const float* __restrict__ bff, const float* __restrict__ bo,
    float* __restrict__ T)                                 // [128][4096] interleaved
{
    __shared__ float e[8][256];
    const int tid = threadIdx.x;
    const int col = blockIdx.x * 256 + tid;                // 0..4095
    const int s0 = blockIdx.y * 8;
    const int j = col >> 2, g = col & 3;
    const float* w = (g == 0 ? wg : g == 1 ? wi : g == 2 ? wf : wo) + (size_t)j * 1280;
    const float bias = (g == 0 ? bg : g == 1 ? bi : g == 2 ? bff : bo)[j];
    #pragma unroll
    for (int i = 0; i < 8; ++i) e[i][tid] = embed[(s0 + i) * 256 + tid];
    __syncthreads();
    const float4* w4 = (const float4*)w;
    float acc[8];
    #pragma unroll
    for (int i = 0; i < 8; ++i) acc[i] = bias;
    for (int d = 0; d < 64; ++d) {
        const float4 wv = w4[d];
        #pragma unroll
        for (int i = 0; i < 8; ++i) {
            const float4 ev = ((const float4*)e[i])[d];
            acc[i] += ev.x * wv.x + ev.y * wv.y + ev.z * wv.z + ev.w * wv.w;
        }
    }
    #pragma unroll
    for (int i = 0; i < 8; ++i)
        T[(size_t)(s0 + i) * 4096 + col] = acc[i];
}

// ---------------- prep 2: pack recurrent weights bf16, gate-interleaved ----
__global__ __launch_bounds__(256) void pack_w(
    const float* __restrict__ wg, const float* __restrict__ wi,
    const float* __restrict__ wf, const float* __restrict__ wo,
    __hip_bfloat16* __restrict__ Wt)                       // [4096][1024]
{
    const int col = blockIdx.x;                            // wcol = j*4+g
    const int j = col >> 2, g = col & 3;
    const float* w = (g == 0 ? wg : g == 1 ? wi : g == 2 ? wf : wo)
                     + (size_t)j * 1280 + 256;             // skip embed part
    __hip_bfloat16* out = Wt + (size_t)col * 1024;
    for (int k = threadIdx.x; k < 1024; k += 256)
        out[k] = __float2bfloat16(w[k]);
}

// ---------------- fused LSTM step ------------------------------------------
// grid 512, 512 threads (8 waves in 4(wm) x 2(wn)); wave tile 32x32, acc[2][2].
// XCD-aware decode: xcd = bid&7 owns wcb in [xcd*4, xcd*4+4), all 16 bb.
// LDS per buffer: Ws 128x64 bf16 (16KB, swizzled) + Hs 64x64 (8KB) = 24KB.
__global__ __launch_bounds__(512, 4) void step_fused(
    const __hip_bfloat16* __restrict__ Wt,   // [4096][1024]
    const float* __restrict__ T,             // [128][4096] interleaved
    const int* __restrict__ X,               // [1024][128]
    const __hip_bfloat16* __restrict__ Hprev,// [1024][1024]
    __hip_bfloat16* __restrict__ Hnext,      // [1024][1024]
    float* __restrict__ CSblob,              // [512*512*4] per-thread cell state
    float* __restrict__ CSout,               // [1024][1024], written at t==127
    int t)
{
    __shared__ char lds[2][24576];           // [buf]{ Ws 16KB | Hs 8KB }
    const int tid = threadIdx.x;
    const int w = tid >> 6, l = tid & 63;
    const int wm = w >> 1, wn = w & 1;
    // XCD-aware decode (dispatch round-robins bid across 8 XCDs):
    const int xcd = blockIdx.x & 7;
    const int q   = blockIdx.x >> 3;         // 0..63 within XCD
    const int wcb = xcd * 4 + (q & 3);       // 0..31 : 4 wcol-blocks per XCD
    const int bb  = q >> 2;                  // 0..15
    const int wcol0 = wcb * 128;
    const int batch0 = bb * 64;

    // slot s: row = s>>3, chunk = s&7 (16B chunks of the 128B row).
    // LDS dest linear in s; global SOURCE chunk is ch^(row&7); reader applies
    // the same XOR -> involution cancels (rule 21).
#define STAGE(K0, BUF) do {                                                    \
        _Pragma("unroll")                                                      \
        for (int i_ = 0; i_ < 2; ++i_) {                                       \
            const int sW = tid + i_ * 512;                                     \
            const int rW = sW >> 3, cW = sW & 7;                               \
            async_copy16(Wt + (size_t)(wcol0 + rW) * 1024 + (K0)               \
                             + ((cW ^ (rW & 7)) << 3),                         \
                         &lds[BUF][sW * 16]);                                  \
        }                                                                      \
        const int sH = tid;                                                    \
        const int rH = sH >> 3, cH = sH & 7;                                   \
        async_copy16(Hprev + (size_t)(batch0 + rH) * 1024 + (K0)               \
                         + ((cH ^ (rH & 7)) << 3),                             \
                     &lds[BUF][16384 + sH * 16]);                              \
    } while (0)

    // ---- epilogue inputs first (retired before staging so vmcnt stays exact)
    int batchN[2], jM[2];
    #pragma unroll
    for (int n = 0; n < 2; ++n) batchN[n] = batch0 + wn * 32 + n * 16 + (l & 15);
    #pragma unroll
    for (int m = 0; m < 2; ++m) jM[m] = (wcol0 >> 2) + wm * 8 + m * 4 + (l >> 4);

    f32x4 tv[2][2];
    float ap[2][2];
    #pragma unroll
    for (int n = 0; n < 2; ++n) {
        const int s = X[batchN[n] * 128 + t];
        #pragma unroll
        for (int m = 0; m < 2; ++m)
            tv[m][n] = *(const f32x4*)&T[(size_t)s * 4096 + jM[m] * 4];
    }
    float* blob = CSblob + ((size_t)blockIdx.x * 512 + tid) * 4;
    if (t > 0) {
        #pragma unroll
        for (int m = 0; m < 2; ++m)
            #pragma unroll
            for (int n = 0; n < 2; ++n) ap[m][n] = blob[m * 2 + n];
    } else {
        #pragma unroll
        for (int m = 0; m < 2; ++m)
            #pragma unroll
            for (int n = 0; n < 2; ++n) ap[m][n] = 0.f;
    }
    asm volatile("s_waitcnt vmcnt(0)" ::: "memory");

    // ---- prologue: tile 0 -------------------------------------------------
    STAGE(0, 0);
    asm volatile("s_waitcnt vmcnt(0)" ::: "memory");
    __builtin_amdgcn_s_barrier();

    f32x4 acc[2][2];
    const f32x4 z4 = {0.f, 0.f, 0.f, 0.f};
    #pragma unroll
    for (int m = 0; m < 2; ++m)
        #pragma unroll
        for (int n = 0; n < 2; ++n) acc[m][n] = z4;

    // ---- K loop: 16 tiles of BK=64, counted-vmcnt, 2 barriers/tile --------
    #pragma unroll
    for (int kt = 0; kt < 16; ++kt) {
        if (kt < 15) STAGE((kt + 1) * 64, (kt + 1) & 1);
        if (kt == 15)     asm volatile("s_waitcnt vmcnt(0)" ::: "memory");
        else if (kt > 0)  asm volatile("s_waitcnt vmcnt(3)" ::: "memory");
        if (kt > 0) __builtin_amdgcn_s_barrier();   // all waves' tile-kt loads in LDS

        const char* base = &lds[kt & 1][0];
        #pragma unroll
        for (int kk = 0; kk < 2; ++kk) {
            bf16x8 af[2], bfr[2];
            #pragma unroll
            for (int m = 0; m < 2; ++m) {
                const int row = wm * 32 + m * 16 + (l & 15);
                const int ch = (kk * 4 + (l >> 4)) ^ (row & 7);
                af[m] = *(const bf16x8*)(base + (row * 8 + ch) * 16);
            }
            #pragma unroll
            for (int n = 0; n < 2; ++n) {
                const int row = wn * 32 + n * 16 + (l & 15);
                const int ch = (kk * 4 + (l >> 4)) ^ (row & 7);
                bfr[n] = *(const bf16x8*)(base + 16384 + (row * 8 + ch) * 16);
            }
            #pragma unroll
            for (int m = 0; m < 2; ++m)
                #pragma unroll
                for (int n = 0; n < 2; ++n)
                    acc[m][n] = __builtin_amdgcn_mfma_f32_16x16x32_bf16(
                        af[m], bfr[n], acc[m][n], 0, 0, 0);
        }
        if (kt < 15) __builtin_amdgcn_s_barrier();  // reads of this buf done
    }
#undef STAGE

    // ---- in-register epilogue --------------------------------------------
    #pragma unroll
    for (int m = 0; m < 2; ++m)
        #pragma unroll
        for (int n = 0; n < 2; ++n) {
            const float z0 = acc[m][n][0] + tv[m][n][0];
            const float z1 = acc[m][n][1] + tv[m][n][1];
            const float z2 = acc[m][n][2] + tv[m][n][2];
            const float z3 = acc[m][n][3] + tv[m][n][3];
            const float gg = tanh_fast(z0);
            const float ii = sigm(z1);
            const float ff = sigm(z2);
            const float oo = sigm(z3);
            const float na = gg * ii + ap[m][n] * ff;
            blob[m * 2 + n] = na;
            Hnext[(size_t)batchN[n] * 1024 + jM[m]] =
                __float2bfloat16(tanh_fast(na) * oo);
            if (t == 127)
                CSout[(size_t)batchN[n] * 1024 + jM[m]] = na;
        }
}

// ---------------- final projection + softmax -------------------------------
__global__ __launch_bounds__(256) void proj_softmax(
    const float* __restrict__ A,             // [1024][1024]
    const float* __restrict__ Wp,            // [10][1024]
    const float* __restrict__ bp,            // [10]
    float* __restrict__ out)                 // [1024][10]
{
    const int row = blockIdx.x;
    const float* a = A + (size_t)row * 1024;
    float p[10];
    #pragma unroll
    for (int c = 0; c < 10; ++c) p[c] = 0.f;
    for (int k = threadIdx.x; k < 1024; k += 256) {
        const float av = a[k];
        #pragma unroll
        for (int c = 0; c < 10; ++c) p[c] += av * Wp[c * 1024 + k];
    }
    #pragma unroll
    for (int c = 0; c < 10; ++c)
        #pragma unroll
        for (int off = 32; off; off >>= 1) p[c] += __shfl_down(p[c], off);
    __shared__ float red[4][10];
    const int wv = threadIdx.x >> 6, ln = threadIdx.x & 63;
    if (ln == 0)
        for (int c = 0; c < 10; ++c) red[wv][c] = p[c];
    __syncthreads();
    if (threadIdx.x == 0) {
        float logits[10], mx = -1e30f;
        for (int c = 0; c < 10; ++c) {
            logits[c] = red[0][c] + red[1][c] + red[2][c] + red[3][c] + bp[c];
            mx = fmaxf(mx, logits[c]);
        }
        float sum = 0.f;
        for (int c = 0; c < 10; ++c) { logits[c] = __expf(logits[c] - mx); sum += logits[c]; }
        const float inv = 1.f / sum;
        for (int c = 0; c < 10; ++c) out[(size_t)row * 10 + c] = logits[c] * inv;
    }
}

// ---------------------------------------------------------------------------
extern "C" void kernel_launch(void* const* d_in, const int* in_sizes, int n_in,
                              void* d_out, int out_size, void* d_ws, size_t ws_size,
                              hipStream_t stream) {
    (void)in_sizes; (void)n_in; (void)out_size; (void)ws_size;
    const int*   x     = (const int*)d_in[0];
    const float* embed = (const float*)d_in[1];
    const float* wg    = (const float*)d_in[2];
    const float* wi    = (const float*)d_in[3];
    const float* wf    = (const float*)d_in[4];
    const float* wo    = (const float*)d_in[5];
    const float* bg    = (const float*)d_in[6];
    const float* bi    = (const float*)d_in[7];
    const float* bff   = (const float*)d_in[8];
    const float* bo    = (const float*)d_in[9];
    const float* wp    = (const float*)d_in[10];
    const float* bp    = (const float*)d_in[11];
    float* out = (float*)d_out;

    char* ws = (char*)d_ws;
    float*          T    = (float*)(ws);                        // 2 MB
    __hip_bfloat16* Wt   = (__hip_bfloat16*)(ws + (2u << 20));  // 8 MB
    __hip_bfloat16* BhA  = (__hip_bfloat16*)(ws + (10u << 20)); // 2 MB
    __hip_bfloat16* BhB  = (__hip_bfloat16*)(ws + (12u << 20)); // 2 MB
    float*          CSo  = (float*)(ws + (14u << 20));          // 4 MB
    float*          CSb  = (float*)(ws + (18u << 20));          // 4 MB

    prep_table<<<dim3(16, 16), 256, 0, stream>>>(embed, wg, wi, wf, wo, bg, bi, bff, bo, T);
    pack_w<<<4096, 256, 0, stream>>>(wg, wi, wf, wo, Wt);
    hipMemsetAsync(BhA, 0, (size_t)1024 * 1024 * sizeof(__hip_bfloat16), stream);

    for (int t = 0; t < 128; ++t) {
        const __hip_bfloat16* Hp = (t & 1) ? BhB : BhA;
        __hip_bfloat16*       Hn = (t & 1) ? BhA : BhB;
        step_fused<<<512, 512, 0, stream>>>(Wt, T, x, Hp, Hn, CSb, CSo, t);
    }
    proj_softmax<<<1024, 256, 0, stream>>>(CSo, wp, bp, out);
}